// Round 14
// baseline (3861.592 us; speedup 1.0000x reference)
//
#include <hip/hip_runtime.h>
#include <math.h>

// Problem constants
static constexpr int cB = 32;
static constexpr int cT = 1024;
static constexpr int cH = 128;
static constexpr int cD = 256;   // 2H
static constexpr int cN = 2048;  // H*POOL
static constexpr int cM = cB * cT; // 32768

typedef __attribute__((ext_vector_type(8))) short short8;
typedef __attribute__((ext_vector_type(4))) float f32x4;

__device__ __forceinline__ ushort f2bf(float x) {
    union { float f; unsigned u; } v; v.f = x;
    unsigned r = v.u + 0x7FFF + ((v.u >> 16) & 1);   // RNE to bf16
    return (ushort)(r >> 16);
}
__device__ __forceinline__ float bf2f(ushort h) {
    union { float f; unsigned u; } v; v.u = ((unsigned)h) << 16;
    return v.f;
}

// async global->LDS, 16B per lane, wave-uniform LDS base + lane*16
__device__ __forceinline__ void gload_lds16(const ushort* g, ushort* l) {
    __builtin_amdgcn_global_load_lds(
        (const __attribute__((address_space(1))) unsigned int*)(const void*)g,
        (__attribute__((address_space(3))) unsigned int*)(void*)l,
        16, 0, 0);
}

// ---------------------------------------------------------------------------
// Pooled swapped GEMM v2 — LDS-ratio-balanced wave tile (r13 diagnosis:
// 8 ds_read per 48 MFMA = 6:1 capped MfmaUtil at ~22%; now 4 reads per 48
// MFMA = 12:1 -> LDS 384 cyc/CU < MFMA wall 466 cyc per k-step).
//   out[m][o] = max_{p<16}( sum_k X[m][k]*Wt[16o+p][k] + initv[ib][16o+p] )
// Geometry: block = 32 n-cols x 512 m-rows, 4 waves (wave = 128 m-rows),
// per wave rf=2 (n frags) x cf=8 (m frags), K/32 k-steps, acc[2][8].
// W panel (32 x K, hi/lo) staged to LDS ONCE (16-32KB), ONE barrier, then
// the k-loop streams X fragments from global (L2-resident) -> regs.
// Swapped orientation mfma(W,X): D row=n col=m -> pool = 3 in-lane fmax +
// shfl_xor(16,32). 3-term split wh*xh+wl*xh+wh*xl, fp32 acc.
// Grid 4096 (64 bx x 64 by), bijective XCD-chunked remap: per XCD, bx sweeps
// fastest -> active set = 512 X rows (0.5-1MB) + W (1-2MB) L2-resident.
// LDS swizzle: 16B-chunk slot s of row r holds logical chunk s^(r&7);
// read applies the same XOR -> 2-way conflicts (free).
// ---------------------------------------------------------------------------
template<int K, bool WRITE_HL>
__global__ __launch_bounds__(256, 2)
void mfma_pool_v2(const ushort* __restrict__ Wth, const ushort* __restrict__ Wtl,
                  const ushort* __restrict__ Xh, const ushort* __restrict__ Xl,
                  const float* __restrict__ initv, int init_bstride,
                  float* __restrict__ out, ushort* __restrict__ outh,
                  ushort* __restrict__ outl)
{
    constexpr int KS = K / 32;                   // k-steps (4 or 8)
    __shared__ __attribute__((aligned(16))) ushort sWh[32 * K];
    __shared__ __attribute__((aligned(16))) ushort sWl[32 * K];

    const int tid  = threadIdx.x;
    const int wave = tid >> 6;          // 0..3 -> m quarter
    const int lane = tid & 63;
    const int l15  = lane & 15;
    const int lg   = lane >> 4;

    const int wg  = blockIdx.x;                  // grid 4096
    const int lin = (wg & 7) * 512 + (wg >> 3);  // XCD-chunked, bijective
    const int bx  = lin & 63;                    // n block (32 cols)
    const int by  = lin >> 6;                    // m block (512 rows)
    const int n0  = bx * 32;
    const int m0  = by * 512;
    const size_t ibase = (size_t)(m0 >> 10) * init_bstride;

    // init values per (rf, reg r): n = n0 + rf*16 + lg*4 + r
    float ivv[2][4];
    #pragma unroll
    for (int rf = 0; rf < 2; ++rf)
        #pragma unroll
        for (int r = 0; r < 4; ++r)
            ivv[rf][r] = initv[ibase + n0 + rf * 16 + lg * 4 + r];

    // ---- stage W panel once: per plane 32 rows x K ushorts ----------------
    // K=256: 16 x 1KB instrs (2 rows each); K=128: 8 x 1KB (4 rows each).
    // LDS linear: (row, slot) at row*K + slot*8; dst = base + lane*8. The
    // global source fetches logical chunk ck = slot ^ (row&7)  (T21).
    if constexpr (K == 256) {
        #pragma unroll
        for (int j = 0; j < 4; ++j) {
            int i   = wave * 4 + j;             // 0..15 per plane
            int row = i * 2 + (lane >> 5);
            int ck  = (lane & 31) ^ (row & 7);
            size_t goff = (size_t)(n0 + row) * K + ck * 8;
            gload_lds16(Wth + goff, sWh + i * 512);
            gload_lds16(Wtl + goff, sWl + i * 512);
        }
    } else {
        #pragma unroll
        for (int j = 0; j < 2; ++j) {
            int i   = wave * 2 + j;             // 0..7 per plane
            int row = i * 4 + (lane >> 4);
            int ck  = (lane & 15) ^ (row & 7);
            size_t goff = (size_t)(n0 + row) * K + ck * 8;
            gload_lds16(Wth + goff, sWh + i * 512);
            gload_lds16(Wtl + goff, sWl + i * 512);
        }
    }
    __syncthreads();        // ONLY barrier: W valid, read-only afterwards

    f32x4 acc[2][8];    // [rf][cf]
    #pragma unroll
    for (int rf = 0; rf < 2; ++rf)
        #pragma unroll
        for (int cf = 0; cf < 8; ++cf)
            acc[rf][cf] = (f32x4){0.f, 0.f, 0.f, 0.f};

    #pragma unroll
    for (int ks = 0; ks < KS; ++ks) {
        // X fragments for this k-step (16 global loads, L2-resident)
        short8 xh_[8], xl_[8];
        #pragma unroll
        for (int cf = 0; cf < 8; ++cf) {
            size_t off = (size_t)(m0 + wave * 128 + cf * 16 + l15) * K
                       + ks * 32 + lg * 8;
            xh_[cf] = *(const short8*)(Xh + off);
            xl_[cf] = *(const short8*)(Xl + off);
        }
        // W fragments from LDS (4 reads -> 48 MFMAs)
        short8 w_h[2], w_l[2];
        #pragma unroll
        for (int rf = 0; rf < 2; ++rf) {
            int row  = rf * 16 + l15;
            int ck2  = ks * 4 + lg;
            int adr  = row * K + ((ck2 ^ (row & 7)) * 8);
            w_h[rf] = *(const short8*)(sWh + adr);
            w_l[rf] = *(const short8*)(sWl + adr);
        }
        #pragma unroll
        for (int rf = 0; rf < 2; ++rf)
            #pragma unroll
            for (int cf = 0; cf < 8; ++cf) {
                acc[rf][cf] = __builtin_amdgcn_mfma_f32_16x16x32_bf16(
                    w_h[rf], xh_[cf], acc[rf][cf], 0, 0, 0);
                acc[rf][cf] = __builtin_amdgcn_mfma_f32_16x16x32_bf16(
                    w_l[rf], xh_[cf], acc[rf][cf], 0, 0, 0);
                acc[rf][cf] = __builtin_amdgcn_mfma_f32_16x16x32_bf16(
                    w_h[rf], xl_[cf], acc[rf][cf], 0, 0, 0);
            }
    }

    // epilogue: in-lane pool over reg r + shfl over lg; lanes 0-15 store
    const int NP = 128;
    #pragma unroll
    for (int rf = 0; rf < 2; ++rf) {
        const int o2 = bx * 2 + rf;
        #pragma unroll
        for (int cf = 0; cf < 8; ++cf) {
            float v0 = acc[rf][cf][0] + ivv[rf][0];
            float v1 = acc[rf][cf][1] + ivv[rf][1];
            float v2 = acc[rf][cf][2] + ivv[rf][2];
            float v3 = acc[rf][cf][3] + ivv[rf][3];
            float mx = fmaxf(fmaxf(v0, v1), fmaxf(v2, v3));
            mx = fmaxf(mx, __shfl_xor(mx, 16));
            mx = fmaxf(mx, __shfl_xor(mx, 32));
            if (lane < 16) {
                int m = m0 + wave * 128 + cf * 16 + lane;
                size_t o = (size_t)m * NP + o2;
                out[o] = mx;
                if (WRITE_HL) {
                    ushort hb = f2bf(mx);
                    outh[o] = hb;
                    outl[o] = f2bf(mx - bf2f(hb));
                }
            }
        }
    }
}

// ---------------------------------------------------------------------------
// Weight transpose + bf16 split: W[K x N] row-major -> Wt hi/lo [N][K]
// ---------------------------------------------------------------------------
__global__ void wsplit_kernel(const float* __restrict__ W, int K, int N,
                              ushort* __restrict__ th, ushort* __restrict__ tl)
{
    int idx = blockIdx.x * 256 + threadIdx.x;
    if (idx >= K * N) return;
    int k = idx / N, n = idx - k * N;      // coalesced read
    float x = W[idx];
    ushort h = f2bf(x);
    th[(size_t)n * K + k] = h;
    tl[(size_t)n * K + k] = f2bf(x - bf2f(h));
}

// ---------------------------------------------------------------------------
// U split: U fp32 [M][256] -> Uh/Ul bf16 same layout
// ---------------------------------------------------------------------------
__global__ void usplit_kernel(const float* __restrict__ U,
                              ushort* __restrict__ uh, ushort* __restrict__ ul)
{
    int idx = blockIdx.x * 256 + threadIdx.x;   // cM*cD threads
    float x = U[idx];
    ushort h = f2bf(x);
    uh[idx] = h;
    ul[idx] = f2bf(x - bf2f(h));
}

// ---------------------------------------------------------------------------
// r[b][j] = tanh( concat([h,us,ue])[b] . WDw[:,j] + WDb[j] )
// ---------------------------------------------------------------------------
__global__ void r_kernel(const float* __restrict__ h, const float* __restrict__ us,
                         const float* __restrict__ ue,
                         const float* __restrict__ WDw, const float* __restrict__ WDb,
                         float* __restrict__ r)
{
    int b = blockIdx.x;
    int j = threadIdx.x;  // 128 threads
    __shared__ float x[640];
    x[j]       = h[b * cH + j];
    x[128 + j] = us[b * cD + j];
    x[256 + j] = us[b * cD + 128 + j];
    x[384 + j] = ue[b * cD + j];
    x[512 + j] = ue[b * cD + 128 + j];
    __syncthreads();
    float s = WDb[j];
    for (int k = 0; k < 640; ++k) s = fmaf(x[k], WDw[(size_t)k * cH + j], s);
    r[b * cH + j] = tanhf(s);
}

// ---------------------------------------------------------------------------
// rterm[b][n] = r[b] . W1r[:,n] + W1b[n]    (W1r = rows 256..383 of W1w)
// ---------------------------------------------------------------------------
__global__ void rterm_kernel(const float* __restrict__ r, const float* __restrict__ W1r,
                             const float* __restrict__ W1b, float* __restrict__ rterm)
{
    int b = blockIdx.y;
    int n = blockIdx.x * 256 + threadIdx.x;  // grid (8,32)
    __shared__ float rs[128];
    if (threadIdx.x < 128) rs[threadIdx.x] = r[b * cH + threadIdx.x];
    __syncthreads();
    float s = W1b[n];
    for (int k = 0; k < 128; ++k) s = fmaf(rs[k], W1r[(size_t)k * cN + n], s);
    rterm[(size_t)b * cN + n] = s;
}

// ---------------------------------------------------------------------------
// score[m] = max_p( concat([m1,m2])[m] . W3w[:,p] + W3b[p] ) -> ent region
// ---------------------------------------------------------------------------
__global__ __launch_bounds__(256)
void score_kernel(const float* __restrict__ m1, const float* __restrict__ m2,
                  const float* __restrict__ W3w, const float* __restrict__ W3b,
                  float* __restrict__ ent)
{
    __shared__ float xs[16][257];
    __shared__ float wsh[256 * 16];
    int tid = threadIdx.x;
    int m0 = blockIdx.x * 16;
    #pragma unroll
    for (int q = 0; q < 16; ++q) wsh[tid + q * 256] = W3w[tid + q * 256];
    #pragma unroll
    for (int q = 0; q < 8; ++q) {
        int f = tid + q * 256;
        int rl = f >> 7, col = f & 127;
        xs[rl][col]       = m1[(size_t)(m0 + rl) * cH + col];
        xs[rl][128 + col] = m2[(size_t)(m0 + rl) * cH + col];
    }
    __syncthreads();
    int rl = tid >> 4, p = tid & 15;
    float s = W3b[p];
    for (int k = 0; k < 256; ++k) s = fmaf(xs[rl][k], wsh[k * 16 + p], s);
    #pragma unroll
    for (int off = 8; off; off >>= 1) s = fmaxf(s, __shfl_xor(s, off));
    if (p == 0) ent[m0 + rl] = s;
}

// ---------------------------------------------------------------------------
// argmax over T per batch (first-occurrence ties), write float index,
// gather U row into us/ue
// ---------------------------------------------------------------------------
__global__ void argmax_kernel(const float* __restrict__ sc, const float* __restrict__ U,
                              float* __restrict__ uvec, float* __restrict__ outidx)
{
    int b = blockIdx.x;
    int tid = threadIdx.x;  // 256
    float bv = -3.4e38f;
    int bi = 0x7fffffff;
    for (int t = tid; t < cT; t += 256) {
        float v = sc[b * cT + t];
        if (v > bv || (v == bv && t < bi)) { bv = v; bi = t; }
    }
    __shared__ float vs[256];
    __shared__ int   is[256];
    vs[tid] = bv; is[tid] = bi;
    __syncthreads();
    for (int s = 128; s > 0; s >>= 1) {
        if (tid < s) {
            if (vs[tid + s] > vs[tid] ||
                (vs[tid + s] == vs[tid] && is[tid + s] < is[tid])) {
                vs[tid] = vs[tid + s];
                is[tid] = is[tid + s];
            }
        }
        __syncthreads();
    }
    int best = is[0];
    if (tid == 0) outidx[b] = (float)best;
    uvec[b * cD + tid % cD] = U[((size_t)b * cT + best) * cD + (tid % cD)];
}

// ---------------------------------------------------------------------------
// LSTM cell
// ---------------------------------------------------------------------------
__global__ void lstm_kernel(const float* __restrict__ us, const float* __restrict__ ue,
                            float* __restrict__ h, float* __restrict__ c,
                            const float* __restrict__ wih, const float* __restrict__ whh,
                            const float* __restrict__ bih, const float* __restrict__ bhh)
{
    int b = blockIdx.x;
    int j = threadIdx.x;  // 128
    __shared__ float x[512];
    __shared__ float hh[128];
    x[j]       = us[b * cD + j];
    x[128 + j] = us[b * cD + 128 + j];
    x[256 + j] = ue[b * cD + j];
    x[384 + j] = ue[b * cD + 128 + j];
    hh[j] = h[b * cH + j];
    __syncthreads();
    float g4[4];
    #pragma unroll
    for (int gi = 0; gi < 4; ++gi) {
        int row = gi * 128 + j;
        float s = bih[row] + bhh[row];
        const float* wr = wih + (size_t)row * 512;
        for (int k = 0; k < 512; ++k) s = fmaf(x[k], wr[k], s);
        const float* wr2 = whh + (size_t)row * 128;
        for (int k = 0; k < 128; ++k) s = fmaf(hh[k], wr2[k], s);
        g4[gi] = s;
    }
    float i_ = 1.f / (1.f + expf(-g4[0]));
    float f_ = 1.f / (1.f + expf(-g4[1]));
    float g_ = tanhf(g4[2]);
    float o_ = 1.f / (1.f + expf(-g4[3]));
    float c2 = f_ * c[b * cH + j] + i_ * g_;
    float h2 = o_ * tanhf(c2);
    c[b * cH + j] = c2;
    h[b * cH + j] = h2;
}

__global__ void init_kernel(const float* __restrict__ U, float* __restrict__ us,
                            float* __restrict__ ue, float* __restrict__ h,
                            float* __restrict__ c)
{
    int i = blockIdx.x * 256 + threadIdx.x;  // 8192 threads
    if (i < cB * cD) {
        int b = i >> 8, d = i & 255;
        us[i] = U[((size_t)b * cT + 0) * cD + d];
        ue[i] = U[((size_t)b * cT + 1) * cD + d];
    }
    if (i < cB * cH) { h[i] = 0.f; c[i] = 0.f; }
}

// ---------------------------------------------------------------------------
extern "C" void kernel_launch(void* const* d_in, const int* in_sizes, int n_in,
                              void* d_out, int out_size, void* d_ws, size_t ws_size,
                              hipStream_t stream)
{
    const float* U = (const float*)d_in[0];
    const float* WD_w[2] = {(const float*)d_in[1], (const float*)d_in[9]};
    const float* WD_b[2] = {(const float*)d_in[2], (const float*)d_in[10]};
    const float* W1_w[2] = {(const float*)d_in[3], (const float*)d_in[11]};
    const float* W1_b[2] = {(const float*)d_in[4], (const float*)d_in[12]};
    const float* W2_w[2] = {(const float*)d_in[5], (const float*)d_in[13]};
    const float* W2_b[2] = {(const float*)d_in[6], (const float*)d_in[14]};
    const float* W3_w[2] = {(const float*)d_in[7], (const float*)d_in[15]};
    const float* W3_b[2] = {(const float*)d_in[8], (const float*)d_in[16]};
    const float* wih = (const float*)d_in[17];
    const float* whh = (const float*)d_in[18];
    const float* bih = (const float*)d_in[19];
    const float* bhh = (const float*)d_in[20];

    float* ws = (float*)d_ws;
    float* m1 = ws;                               // 4M floats
    float* m2 = m1 + (size_t)cM * cH;             // 4M
    float* us = m2 + (size_t)cM * cH;
    float* ue = us + cB * cD;
    float* h  = ue + cB * cD;
    float* c  = h + cB * cH;
    float* r  = c + cB * cH;
    float* rterm = r + cB * cH;                   // 64K
    float* cur = rterm + (size_t)cB * cN;

    ushort* m1h = (ushort*)cur;                   cur += (size_t)cM * cH / 2;
    ushort* m1l = (ushort*)cur;                   cur += (size_t)cM * cH / 2;
    ushort* Uh  = (ushort*)cur;                   cur += (size_t)cM * cD / 2;
    ushort* Ul  = (ushort*)cur;                   cur += (size_t)cM * cD / 2;
    ushort* W1th[2], *W1tl[2], *W2th[2], *W2tl[2];
    for (int sd = 0; sd < 2; ++sd) {
        W1th[sd] = (ushort*)cur; cur += (size_t)cN * cD / 2;   // [2048][256]
        W1tl[sd] = (ushort*)cur; cur += (size_t)cN * cD / 2;
        W2th[sd] = (ushort*)cur; cur += (size_t)cN * cH / 2;   // [2048][128]
        W2tl[sd] = (ushort*)cur; cur += (size_t)cN * cH / 2;
    }

    float* outf = (float*)d_out;

    init_kernel<<<32, 256, 0, stream>>>(U, us, ue, h, c);
    usplit_kernel<<<(cM * cD) / 256, 256, 0, stream>>>(U, Uh, Ul);
    for (int sd = 0; sd < 2; ++sd) {
        wsplit_kernel<<<(cD * cN) / 256, 256, 0, stream>>>(
            W1_w[sd], cD, cN, W1th[sd], W1tl[sd]);     // first 256 rows of W1
        wsplit_kernel<<<(cH * cN) / 256, 256, 0, stream>>>(
            W2_w[sd], cH, cN, W2th[sd], W2tl[sd]);
    }

    const int ggrid = 4096;   // 64 bx x 64 by (XCD swizzle inside)
    for (int it = 0; it < 4; ++it) {
        for (int sd = 0; sd < 2; ++sd) {
            r_kernel<<<32, 128, 0, stream>>>(h, us, ue, WD_w[sd], WD_b[sd], r);
            rterm_kernel<<<dim3(8, 32), 256, 0, stream>>>(
                r, W1_w[sd] + (size_t)256 * cN, W1_b[sd], rterm);
            // m1 = pool(U @ W1[0:256] + rterm) -> fp32 + bf16 hi/lo (fused)
            mfma_pool_v2<256, true><<<ggrid, 256, 0, stream>>>(
                W1th[sd], W1tl[sd], Uh, Ul, rterm, cN, m1, m1h, m1l);
            // m2 = pool(m1 @ W2 + b2) -> fp32
            mfma_pool_v2<128, false><<<ggrid, 256, 0, stream>>>(
                W2th[sd], W2tl[sd], m1h, m1l, W2_b[sd], 0, m2, nullptr, nullptr);
            float* ent = outf + 64 + (size_t)(it * 2 + sd) * cB * cT;
            score_kernel<<<2048, 256, 0, stream>>>(m1, m2, W3_w[sd], W3_b[sd], ent);
            argmax_kernel<<<32, 256, 0, stream>>>(ent, U, sd ? ue : us,
                                                  outf + (sd ? 32 : 0));
        }
        lstm_kernel<<<32, 128, 0, stream>>>(us, ue, h, c, wih, whh, bih, bhh);
    }
}

// Round 16
// 2923.012 us; speedup vs baseline: 1.3211x; 1.3211x over previous
//
#include <hip/hip_runtime.h>
#include <math.h>

// Problem constants
static constexpr int cB = 32;
static constexpr int cT = 1024;
static constexpr int cH = 128;
static constexpr int cD = 256;   // 2H
static constexpr int cN = 2048;  // H*POOL
static constexpr int cM = cB * cT; // 32768

typedef __attribute__((ext_vector_type(8))) short short8;
typedef __attribute__((ext_vector_type(4))) float f32x4;

__device__ __forceinline__ ushort f2bf(float x) {
    union { float f; unsigned u; } v; v.f = x;
    unsigned r = v.u + 0x7FFF + ((v.u >> 16) & 1);   // RNE to bf16
    return (ushort)(r >> 16);
}
__device__ __forceinline__ float bf2f(ushort h) {
    union { float f; unsigned u; } v; v.u = ((unsigned)h) << 16;
    return v.f;
}

// async global->LDS, 16B per lane, wave-uniform LDS base + lane*16
__device__ __forceinline__ void gload_lds16(const ushort* g, ushort* l) {
    __builtin_amdgcn_global_load_lds(
        (const __attribute__((address_space(1))) unsigned int*)(const void*)g,
        (__attribute__((address_space(3))) unsigned int*)(void*)l,
        16, 0, 0);
}

// ---------------------------------------------------------------------------
// SWAPPED pooled fused-m1 GEMM (round-9/12/13 verified config), K=256, with
// runtime m-offset (rows [mOff, cM) — rows below mOff are served by the
// precomputed-A1 memory pass).
//   out[m][o] = max_{p<16}( sum_k X[m][k]*Wt[16o+p][k] + initv[b][16o+p] )
// C^T via mfma(Wfrag, Xfrag): pool = 3 in-lane fmax + shfl_xor(16,32).
// Per 128-k half: stage Wt (64KB hi/lo) via gload_lds + hoist all X frags
// -> ONE barrier -> 4 k-steps of pure ds_read+MFMA. 3-term split, fp32 acc.
// Grid = 16 * mBlocks (runtime), bijective XCD-chunked remap via gridDiv8.
// ---------------------------------------------------------------------------
__global__ __launch_bounds__(256, 2)
void mfma_pool_swp(const ushort* __restrict__ Wth, const ushort* __restrict__ Wtl,
                   const ushort* __restrict__ Xh, const ushort* __restrict__ Xl,
                   const float* __restrict__ initv, int init_bstride,
                   float* __restrict__ out, ushort* __restrict__ outh,
                   ushort* __restrict__ outl, int mOff, int gridDiv8)
{
    constexpr int K = 256;
    __shared__ __attribute__((aligned(16))) ushort sWh[128 * 128];
    __shared__ __attribute__((aligned(16))) ushort sWl[128 * 128];

    const int tid  = threadIdx.x;
    const int wave = tid >> 6;
    const int lane = tid & 63;
    const int l15  = lane & 15;
    const int lg   = lane >> 4;
    const int wr   = wave >> 1;         // n-half
    const int wc   = wave & 1;          // m-half

    const int wg  = blockIdx.x;
    const int lin = (wg & 7) * gridDiv8 + (wg >> 3);   // bijective (grid=8*gridDiv8)
    const int bx  = lin & 15;
    const int by  = lin >> 4;
    const int n0  = bx * 128;
    const int m0  = mOff + by * 128;
    const size_t ibase = (size_t)(m0 >> 10) * init_bstride;

    float ivv[4][4];
    #pragma unroll
    for (int rf = 0; rf < 4; ++rf)
        #pragma unroll
        for (int r = 0; r < 4; ++r)
            ivv[rf][r] = initv[ibase + n0 + wr * 64 + rf * 16 + lg * 4 + r];

    f32x4 acc[4][4];
    #pragma unroll
    for (int rf = 0; rf < 4; ++rf)
        #pragma unroll
        for (int cf = 0; cf < 4; ++cf)
            acc[rf][cf] = (f32x4){0.f, 0.f, 0.f, 0.f};

    const int st_row_lo = lane >> 4;
    const int st_slot   = lane & 15;

    #pragma unroll
    for (int kh = 0; kh < 2; ++kh) {
        const int kb = kh * 128;
        if (kh > 0) __syncthreads();

        #pragma unroll
        for (int j = 0; j < 8; ++j) {
            int i   = wave * 8 + j;
            int row = i * 4 + st_row_lo;
            int ck  = st_slot ^ (row & 7);
            size_t goff = (size_t)(n0 + row) * K + kb + ck * 8;
            gload_lds16(Wth + goff, sWh + i * 512);
            gload_lds16(Wtl + goff, sWl + i * 512);
        }
        short8 xh_[16], xl_[16];
        #pragma unroll
        for (int cf = 0; cf < 4; ++cf)
            #pragma unroll
            for (int ks = 0; ks < 4; ++ks) {
                size_t off = (size_t)(m0 + wc * 64 + cf * 16 + l15) * K
                           + kb + ks * 32 + lg * 8;
                xh_[cf * 4 + ks] = *(const short8*)(Xh + off);
                xl_[cf * 4 + ks] = *(const short8*)(Xl + off);
            }
        __syncthreads();

        #pragma unroll
        for (int ks = 0; ks < 4; ++ks) {
            short8 w_h[4], w_l[4];
            #pragma unroll
            for (int rf = 0; rf < 4; ++rf) {
                int row  = wr * 64 + rf * 16 + l15;
                int ck2  = ks * 4 + lg;
                int adr  = row * 128 + ((ck2 ^ (row & 7)) * 8);
                w_h[rf] = *(const short8*)(sWh + adr);
                w_l[rf] = *(const short8*)(sWl + adr);
            }
            #pragma unroll
            for (int rf = 0; rf < 4; ++rf)
                #pragma unroll
                for (int cf = 0; cf < 4; ++cf) {
                    acc[rf][cf] = __builtin_amdgcn_mfma_f32_16x16x32_bf16(
                        w_h[rf], xh_[cf * 4 + ks], acc[rf][cf], 0, 0, 0);
                    acc[rf][cf] = __builtin_amdgcn_mfma_f32_16x16x32_bf16(
                        w_l[rf], xh_[cf * 4 + ks], acc[rf][cf], 0, 0, 0);
                    acc[rf][cf] = __builtin_amdgcn_mfma_f32_16x16x32_bf16(
                        w_h[rf], xl_[cf * 4 + ks], acc[rf][cf], 0, 0, 0);
                }
        }
    }

    const int NP = 128;
    #pragma unroll
    for (int rf = 0; rf < 4; ++rf) {
        const int o2 = (n0 >> 4) + wr * 4 + rf;
        #pragma unroll
        for (int cf = 0; cf < 4; ++cf) {
            float v0 = acc[rf][cf][0] + ivv[rf][0];
            float v1 = acc[rf][cf][1] + ivv[rf][1];
            float v2 = acc[rf][cf][2] + ivv[rf][2];
            float v3 = acc[rf][cf][3] + ivv[rf][3];
            float mx = fmaxf(fmaxf(v0, v1), fmaxf(v2, v3));
            mx = fmaxf(mx, __shfl_xor(mx, 16));
            mx = fmaxf(mx, __shfl_xor(mx, 32));
            if (lane < 16) {
                int m = m0 + wc * 64 + cf * 16 + lane;
                size_t o = (size_t)m * NP + o2;
                out[o] = mx;
                ushort hb = f2bf(mx);
                outh[o] = hb;
                outl[o] = f2bf(mx - bf2f(hb));
            }
        }
    }
}

// ---------------------------------------------------------------------------
// A1 GEMM, fp32 out (K=256): A1[m][n] = sum_k U[m][k]*W1t[n][k], rows [0,a1r).
// Unswapped orientation — D rows = A(U) rows, cols = B(W) cols; this fragment
// interpretation is validated by rounds 5-8's pooled epilogue (passed).
// fp32 store = exact accumulator, so the A1 path is numerically identical to
// the fused path (r15's bf16-hi A1 flipped argmaxes — reverted).
// ---------------------------------------------------------------------------
__global__ __launch_bounds__(256, 2)
void mfma_gemm_a1(const ushort* __restrict__ Uh, const ushort* __restrict__ Ul,
                  const ushort* __restrict__ Bth, const ushort* __restrict__ Btl,
                  float* __restrict__ out, int gridDiv8)
{
    constexpr int K = 256;
    __shared__ __attribute__((aligned(16))) ushort sBh[128 * 128];
    __shared__ __attribute__((aligned(16))) ushort sBl[128 * 128];

    const int tid  = threadIdx.x;
    const int wave = tid >> 6;
    const int lane = tid & 63;
    const int l15  = lane & 15;
    const int lg   = lane >> 4;
    const int wr   = wave >> 1;         // m-half
    const int wc   = wave & 1;          // n-half

    const int wg  = blockIdx.x;
    const int lin = (wg & 7) * gridDiv8 + (wg >> 3);
    const int bx  = lin & 15;
    const int by  = lin >> 4;
    const int n0  = bx * 128;
    const int m0  = by * 128;

    f32x4 acc[4][4];    // [mf][nf]
    #pragma unroll
    for (int mf = 0; mf < 4; ++mf)
        #pragma unroll
        for (int nf = 0; nf < 4; ++nf)
            acc[mf][nf] = (f32x4){0.f, 0.f, 0.f, 0.f};

    const int st_row_lo = lane >> 4;
    const int st_slot   = lane & 15;

    #pragma unroll
    for (int kh = 0; kh < 2; ++kh) {
        const int kb = kh * 128;
        if (kh > 0) __syncthreads();

        #pragma unroll
        for (int j = 0; j < 8; ++j) {
            int i   = wave * 8 + j;
            int row = i * 4 + st_row_lo;
            int ck  = st_slot ^ (row & 7);
            size_t goff = (size_t)(n0 + row) * K + kb + ck * 8;
            gload_lds16(Bth + goff, sBh + i * 512);
            gload_lds16(Btl + goff, sBl + i * 512);
        }
        short8 ph[16], pl[16];
        #pragma unroll
        for (int mf = 0; mf < 4; ++mf)
            #pragma unroll
            for (int ks = 0; ks < 4; ++ks) {
                size_t off = (size_t)(m0 + wr * 64 + mf * 16 + l15) * K
                           + kb + ks * 32 + lg * 8;
                ph[mf * 4 + ks] = *(const short8*)(Uh + off);
                pl[mf * 4 + ks] = *(const short8*)(Ul + off);
            }
        __syncthreads();

        #pragma unroll
        for (int ks = 0; ks < 4; ++ks) {
            short8 b_h[4], b_l[4];
            #pragma unroll
            for (int nf = 0; nf < 4; ++nf) {
                int row  = wc * 64 + nf * 16 + l15;
                int ck2  = ks * 4 + lg;
                int adr  = row * 128 + ((ck2 ^ (row & 7)) * 8);
                b_h[nf] = *(const short8*)(sBh + adr);
                b_l[nf] = *(const short8*)(sBl + adr);
            }
            #pragma unroll
            for (int mf = 0; mf < 4; ++mf)
                #pragma unroll
                for (int nf = 0; nf < 4; ++nf) {
                    acc[mf][nf] = __builtin_amdgcn_mfma_f32_16x16x32_bf16(
                        ph[mf * 4 + ks], b_h[nf], acc[mf][nf], 0, 0, 0);
                    acc[mf][nf] = __builtin_amdgcn_mfma_f32_16x16x32_bf16(
                        ph[mf * 4 + ks], b_l[nf], acc[mf][nf], 0, 0, 0);
                    acc[mf][nf] = __builtin_amdgcn_mfma_f32_16x16x32_bf16(
                        pl[mf * 4 + ks], b_h[nf], acc[mf][nf], 0, 0, 0);
                }
        }
    }

    #pragma unroll
    for (int mf = 0; mf < 4; ++mf)
        #pragma unroll
        for (int nf = 0; nf < 4; ++nf) {
            int col = n0 + wc * 64 + nf * 16 + l15;
            #pragma unroll
            for (int r = 0; r < 4; ++r) {
                int row = m0 + wr * 64 + mf * 16 + lg * 4 + r;
                out[(size_t)row * cN + col] = acc[mf][nf][r];
            }
        }
}

// ---------------------------------------------------------------------------
// m1[m][o] = max_p( A1[m][o*16+p] + rterm[b][o*16+p] ), fp32 in, emits hi/lo
// ---------------------------------------------------------------------------
__global__ void m1_from_a1_kernel(const float* __restrict__ A1,
                                  const float* __restrict__ rterm,
                                  float* __restrict__ m1,
                                  ushort* __restrict__ m1h,
                                  ushort* __restrict__ m1l)
{
    int idx = blockIdx.x * 256 + threadIdx.x;
    int m = idx >> 7;
    int o = idx & 127;
    int b = m >> 10;
    const float4* a  = (const float4*)(A1 + (size_t)m * cN + o * 16);
    const float4* rt = (const float4*)(rterm + (size_t)b * cN + o * 16);
    float mx = -3.4e38f;
    #pragma unroll
    for (int q = 0; q < 4; ++q) {
        float4 av = a[q];
        float4 rv = rt[q];
        mx = fmaxf(mx, fmaxf(fmaxf(av.x + rv.x, av.y + rv.y),
                             fmaxf(av.z + rv.z, av.w + rv.w)));
    }
    m1[idx] = mx;
    ushort hb = f2bf(mx);
    m1h[idx] = hb;
    m1l[idx] = f2bf(mx - bf2f(hb));
}

// ---------------------------------------------------------------------------
// m2 multi-subtile (K=128, S=4, unroll-1): W2 panel staged ONCE, one barrier,
// then 4 barrier-free subtiles. Grid 1024, 2 blk/CU. (r13 structure.)
// ---------------------------------------------------------------------------
__global__ __launch_bounds__(256, 2)
void mfma_pool_m2(const ushort* __restrict__ Wth, const ushort* __restrict__ Wtl,
                  const ushort* __restrict__ Xh, const ushort* __restrict__ Xl,
                  const float* __restrict__ bias, float* __restrict__ out)
{
    constexpr int K = 128;
    __shared__ __attribute__((aligned(16))) ushort sWh[128 * 128];
    __shared__ __attribute__((aligned(16))) ushort sWl[128 * 128];

    const int tid  = threadIdx.x;
    const int wave = tid >> 6;
    const int lane = tid & 63;
    const int l15  = lane & 15;
    const int lg   = lane >> 4;
    const int wr   = wave >> 1;
    const int wc   = wave & 1;

    const int wg  = blockIdx.x;                  // grid 1024
    const int lin = (wg & 7) * 128 + (wg >> 3);  // XCD-chunked, bijective
    const int bx  = lin & 15;
    const int by  = lin >> 4;                    // m group (512 rows)
    const int n0  = bx * 128;

    float ivv[4][4];
    #pragma unroll
    for (int rf = 0; rf < 4; ++rf)
        #pragma unroll
        for (int r = 0; r < 4; ++r)
            ivv[rf][r] = bias[n0 + wr * 64 + rf * 16 + lg * 4 + r];

    const int st_row_lo = lane >> 4;
    const int st_slot   = lane & 15;
    #pragma unroll
    for (int j = 0; j < 8; ++j) {
        int i   = wave * 8 + j;
        int row = i * 4 + st_row_lo;
        int ck  = st_slot ^ (row & 7);
        size_t goff = (size_t)(n0 + row) * K + ck * 8;
        gload_lds16(Wth + goff, sWh + i * 512);
        gload_lds16(Wtl + goff, sWl + i * 512);
    }
    __syncthreads();        // only barrier: W valid, read-only afterwards

    const int NP = 128;
    #pragma unroll 1
    for (int s = 0; s < 4; ++s) {
        const int m0 = by * 512 + s * 128;

        short8 xh_[16], xl_[16];
        #pragma unroll
        for (int cf = 0; cf < 4; ++cf)
            #pragma unroll
            for (int ks = 0; ks < 4; ++ks) {
                size_t off = (size_t)(m0 + wc * 64 + cf * 16 + l15) * K
                           + ks * 32 + lg * 8;
                xh_[cf * 4 + ks] = *(const short8*)(Xh + off);
                xl_[cf * 4 + ks] = *(const short8*)(Xl + off);
            }

        f32x4 acc[4][4];
        #pragma unroll
        for (int rf = 0; rf < 4; ++rf)
            #pragma unroll
            for (int cf = 0; cf < 4; ++cf)
                acc[rf][cf] = (f32x4){0.f, 0.f, 0.f, 0.f};

        #pragma unroll
        for (int ks = 0; ks < 4; ++ks) {
            short8 w_h[4], w_l[4];
            #pragma unroll
            for (int rf = 0; rf < 4; ++rf) {
                int row  = wr * 64 + rf * 16 + l15;
                int ck2  = ks * 4 + lg;
                int adr  = row * 128 + ((ck2 ^ (row & 7)) * 8);
                w_h[rf] = *(const short8*)(sWh + adr);
                w_l[rf] = *(const short8*)(sWl + adr);
            }
            #pragma unroll
            for (int rf = 0; rf < 4; ++rf)
                #pragma unroll
                for (int cf = 0; cf < 4; ++cf) {
                    acc[rf][cf] = __builtin_amdgcn_mfma_f32_16x16x32_bf16(
                        w_h[rf], xh_[cf * 4 + ks], acc[rf][cf], 0, 0, 0);
                    acc[rf][cf] = __builtin_amdgcn_mfma_f32_16x16x32_bf16(
                        w_l[rf], xh_[cf * 4 + ks], acc[rf][cf], 0, 0, 0);
                    acc[rf][cf] = __builtin_amdgcn_mfma_f32_16x16x32_bf16(
                        w_h[rf], xl_[cf * 4 + ks], acc[rf][cf], 0, 0, 0);
                }
        }

        #pragma unroll
        for (int rf = 0; rf < 4; ++rf) {
            const int o2 = (n0 >> 4) + wr * 4 + rf;
            #pragma unroll
            for (int cf = 0; cf < 4; ++cf) {
                float v0 = acc[rf][cf][0] + ivv[rf][0];
                float v1 = acc[rf][cf][1] + ivv[rf][1];
                float v2 = acc[rf][cf][2] + ivv[rf][2];
                float v3 = acc[rf][cf][3] + ivv[rf][3];
                float mx = fmaxf(fmaxf(v0, v1), fmaxf(v2, v3));
                mx = fmaxf(mx, __shfl_xor(mx, 16));
                mx = fmaxf(mx, __shfl_xor(mx, 32));
                if (lane < 16) {
                    int m = m0 + wc * 64 + cf * 16 + lane;
                    out[(size_t)m * NP + o2] = mx;
                }
            }
        }
    }
}

// ---------------------------------------------------------------------------
// Weight transpose + bf16 split: W[K x N] row-major -> Wt hi/lo [N][K]
// ---------------------------------------------------------------------------
__global__ void wsplit_kernel(const float* __restrict__ W, int K, int N,
                              ushort* __restrict__ th, ushort* __restrict__ tl)
{
    int idx = blockIdx.x * 256 + threadIdx.x;
    if (idx >= K * N) return;
    int k = idx / N, n = idx - k * N;      // coalesced read
    float x = W[idx];
    ushort h = f2bf(x);
    th[(size_t)n * K + k] = h;
    tl[(size_t)n * K + k] = f2bf(x - bf2f(h));
}

// ---------------------------------------------------------------------------
// U split: U fp32 [M][256] -> Uh/Ul bf16 same layout
// ---------------------------------------------------------------------------
__global__ void usplit_kernel(const float* __restrict__ U,
                              ushort* __restrict__ uh, ushort* __restrict__ ul)
{
    int idx = blockIdx.x * 256 + threadIdx.x;   // cM*cD threads
    float x = U[idx];
    ushort h = f2bf(x);
    uh[idx] = h;
    ul[idx] = f2bf(x - bf2f(h));
}

// ---------------------------------------------------------------------------
// r[b][j] = tanh( concat([h,us,ue])[b] . WDw[:,j] + WDb[j] )
// ---------------------------------------------------------------------------
__global__ void r_kernel(const float* __restrict__ h, const float* __restrict__ us,
                         const float* __restrict__ ue,
                         const float* __restrict__ WDw, const float* __restrict__ WDb,
                         float* __restrict__ r)
{
    int b = blockIdx.x;
    int j = threadIdx.x;  // 128 threads
    __shared__ float x[640];
    x[j]       = h[b * cH + j];
    x[128 + j] = us[b * cD + j];
    x[256 + j] = us[b * cD + 128 + j];
    x[384 + j] = ue[b * cD + j];
    x[512 + j] = ue[b * cD + 128 + j];
    __syncthreads();
    float s = WDb[j];
    for (int k = 0; k < 640; ++k) s = fmaf(x[k], WDw[(size_t)k * cH + j], s);
    r[b * cH + j] = tanhf(s);
}

// ---------------------------------------------------------------------------
// rterm[b][n] = r[b] . W1r[:,n] + W1b[n]    (W1r = rows 256..383 of W1w)
// ---------------------------------------------------------------------------
__global__ void rterm_kernel(const float* __restrict__ r, const float* __restrict__ W1r,
                             const float* __restrict__ W1b, float* __restrict__ rterm)
{
    int b = blockIdx.y;
    int n = blockIdx.x * 256 + threadIdx.x;  // grid (8,32)
    __shared__ float rs[128];
    if (threadIdx.x < 128) rs[threadIdx.x] = r[b * cH + threadIdx.x];
    __syncthreads();
    float s = W1b[n];
    for (int k = 0; k < 128; ++k) s = fmaf(rs[k], W1r[(size_t)k * cN + n], s);
    rterm[(size_t)b * cN + n] = s;
}

// ---------------------------------------------------------------------------
// score[m] = max_p( concat([m1,m2])[m] . W3w[:,p] + W3b[p] ) -> ent region
// ---------------------------------------------------------------------------
__global__ __launch_bounds__(256)
void score_kernel(const float* __restrict__ m1, const float* __restrict__ m2,
                  const float* __restrict__ W3w, const float* __restrict__ W3b,
                  float* __restrict__ ent)
{
    __shared__ float xs[16][257];
    __shared__ float wsh[256 * 16];
    int tid = threadIdx.x;
    int m0 = blockIdx.x * 16;
    #pragma unroll
    for (int q = 0; q < 16; ++q) wsh[tid + q * 256] = W3w[tid + q * 256];
    #pragma unroll
    for (int q = 0; q < 8; ++q) {
        int f = tid + q * 256;
        int rl = f >> 7, col = f & 127;
        xs[rl][col]       = m1[(size_t)(m0 + rl) * cH + col];
        xs[rl][128 + col] = m2[(size_t)(m0 + rl) * cH + col];
    }
    __syncthreads();
    int rl = tid >> 4, p = tid & 15;
    float s = W3b[p];
    for (int k = 0; k < 256; ++k) s = fmaf(xs[rl][k], wsh[k * 16 + p], s);
    #pragma unroll
    for (int off = 8; off; off >>= 1) s = fmaxf(s, __shfl_xor(s, off));
    if (p == 0) ent[m0 + rl] = s;
}

// ---------------------------------------------------------------------------
// argmax over T per batch (first-occurrence ties), write float index,
// gather U row into us/ue
// ---------------------------------------------------------------------------
__global__ void argmax_kernel(const float* __restrict__ sc, const float* __restrict__ U,
                              float* __restrict__ uvec, float* __restrict__ outidx)
{
    int b = blockIdx.x;
    int tid = threadIdx.x;  // 256
    float bv = -3.4e38f;
    int bi = 0x7fffffff;
    for (int t = tid; t < cT; t += 256) {
        float v = sc[b * cT + t];
        if (v > bv || (v == bv && t < bi)) { bv = v; bi = t; }
    }
    __shared__ float vs[256];
    __shared__ int   is[256];
    vs[tid] = bv; is[tid] = bi;
    __syncthreads();
    for (int s = 128; s > 0; s >>= 1) {
        if (tid < s) {
            if (vs[tid + s] > vs[tid] ||
                (vs[tid + s] == vs[tid] && is[tid + s] < is[tid])) {
                vs[tid] = vs[tid + s];
                is[tid] = is[tid + s];
            }
        }
        __syncthreads();
    }
    int best = is[0];
    if (tid == 0) outidx[b] = (float)best;
    uvec[b * cD + tid % cD] = U[((size_t)b * cT + best) * cD + (tid % cD)];
}

// ---------------------------------------------------------------------------
// LSTM cell
// ---------------------------------------------------------------------------
__global__ void lstm_kernel(const float* __restrict__ us, const float* __restrict__ ue,
                            float* __restrict__ h, float* __restrict__ c,
                            const float* __restrict__ wih, const float* __restrict__ whh,
                            const float* __restrict__ bih, const float* __restrict__ bhh)
{
    int b = blockIdx.x;
    int j = threadIdx.x;  // 128
    __shared__ float x[512];
    __shared__ float hh[128];
    x[j]       = us[b * cD + j];
    x[128 + j] = us[b * cD + 128 + j];
    x[256 + j] = ue[b * cD + j];
    x[384 + j] = ue[b * cD + 128 + j];
    hh[j] = h[b * cH + j];
    __syncthreads();
    float g4[4];
    #pragma unroll
    for (int gi = 0; gi < 4; ++gi) {
        int row = gi * 128 + j;
        float s = bih[row] + bhh[row];
        const float* wr = wih + (size_t)row * 512;
        for (int k = 0; k < 512; ++k) s = fmaf(x[k], wr[k], s);
        const float* wr2 = whh + (size_t)row * 128;
        for (int k = 0; k < 128; ++k) s = fmaf(hh[k], wr2[k], s);
        g4[gi] = s;
    }
    float i_ = 1.f / (1.f + expf(-g4[0]));
    float f_ = 1.f / (1.f + expf(-g4[1]));
    float g_ = tanhf(g4[2]);
    float o_ = 1.f / (1.f + expf(-g4[3]));
    float c2 = f_ * c[b * cH + j] + i_ * g_;
    float h2 = o_ * tanhf(c2);
    c[b * cH + j] = c2;
    h[b * cH + j] = h2;
}

__global__ void init_kernel(const float* __restrict__ U, float* __restrict__ us,
                            float* __restrict__ ue, float* __restrict__ h,
                            float* __restrict__ c)
{
    int i = blockIdx.x * 256 + threadIdx.x;  // 8192 threads
    if (i < cB * cD) {
        int b = i >> 8, d = i & 255;
        us[i] = U[((size_t)b * cT + 0) * cD + d];
        ue[i] = U[((size_t)b * cT + 1) * cD + d];
    }
    if (i < cB * cH) { h[i] = 0.f; c[i] = 0.f; }
}

// ---------------------------------------------------------------------------
extern "C" void kernel_launch(void* const* d_in, const int* in_sizes, int n_in,
                              void* d_out, int out_size, void* d_ws, size_t ws_size,
                              hipStream_t stream)
{
    const float* U = (const float*)d_in[0];
    const float* WD_w[2] = {(const float*)d_in[1], (const float*)d_in[9]};
    const float* WD_b[2] = {(const float*)d_in[2], (const float*)d_in[10]};
    const float* W1_w[2] = {(const float*)d_in[3], (const float*)d_in[11]};
    const float* W1_b[2] = {(const float*)d_in[4], (const float*)d_in[12]};
    const float* W2_w[2] = {(const float*)d_in[5], (const float*)d_in[13]};
    const float* W2_b[2] = {(const float*)d_in[6], (const float*)d_in[14]};
    const float* W3_w[2] = {(const float*)d_in[7], (const float*)d_in[15]};
    const float* W3_b[2] = {(const float*)d_in[8], (const float*)d_in[16]};
    const float* wih = (const float*)d_in[17];
    const float* whh = (const float*)d_in[18];
    const float* bih = (const float*)d_in[19];
    const float* bhh = (const float*)d_in[20];

    float* ws = (float*)d_ws;
    float* m1 = ws;                               // 4M floats
    float* m2 = m1 + (size_t)cM * cH;             // 4M
    float* us = m2 + (size_t)cM * cH;
    float* ue = us + cB * cD;
    float* h  = ue + cB * cD;
    float* c  = h + cB * cH;
    float* r  = c + cB * cH;
    float* rterm = r + cB * cH;                   // 64K
    float* cur = rterm + (size_t)cB * cN;

    ushort* m1h = (ushort*)cur;                   cur += (size_t)cM * cH / 2;
    ushort* m1l = (ushort*)cur;                   cur += (size_t)cM * cH / 2;
    ushort* Uh  = (ushort*)cur;                   cur += (size_t)cM * cD / 2;
    ushort* Ul  = (ushort*)cur;                   cur += (size_t)cM * cD / 2;
    ushort* W1th[2], *W1tl[2], *W2th[2], *W2tl[2];
    for (int sd = 0; sd < 2; ++sd) {
        W1th[sd] = (ushort*)cur; cur += (size_t)cN * cD / 2;   // [2048][256]
        W1tl[sd] = (ushort*)cur; cur += (size_t)cN * cD / 2;
        W2th[sd] = (ushort*)cur; cur += (size_t)cN * cH / 2;   // [2048][128]
        W2tl[sd] = (ushort*)cur; cur += (size_t)cN * cH / 2;
    }

    // Partial fp32 A1 precompute, adaptively sized to remaining workspace.
    // r15 evidence: ws in [221MB, 355MB) -> 16K-32K of 32K rows covered.
    size_t baseBytes = (size_t)((char*)cur - (char*)ws);
    size_t rowBytes  = (size_t)cN * sizeof(float);   // 8KB per A1 row
    size_t availRows = ws_size > baseBytes ? (ws_size - baseBytes) / rowBytes : 0;
    int a1r[2];
    a1r[0] = (int)((availRows > (size_t)cM ? (size_t)cM : availRows) & ~(size_t)127);
    size_t rem = availRows - (size_t)a1r[0];
    a1r[1] = (int)((rem > (size_t)cM ? (size_t)cM : rem) & ~(size_t)127);
    float* A1[2];
    A1[0] = (float*)cur;
    A1[1] = A1[0] + (size_t)a1r[0] * cN;

    float* outf = (float*)d_out;

    init_kernel<<<32, 256, 0, stream>>>(U, us, ue, h, c);
    usplit_kernel<<<(cM * cD) / 256, 256, 0, stream>>>(U, Uh, Ul);
    for (int sd = 0; sd < 2; ++sd) {
        wsplit_kernel<<<(cD * cN) / 256, 256, 0, stream>>>(
            W1_w[sd], cD, cN, W1th[sd], W1tl[sd]);     // first 256 rows of W1
        wsplit_kernel<<<(cH * cN) / 256, 256, 0, stream>>>(
            W2_w[sd], cH, cN, W2th[sd], W2tl[sd]);
    }

    // Build partial A1 (rows [0, a1r[sd])) once per weight set.
    for (int sd = 0; sd < 2; ++sd)
        if (a1r[sd] > 0) {
            int mB = a1r[sd] / 128;
            mfma_gemm_a1<<<16 * mB, 256, 0, stream>>>(
                Uh, Ul, W1th[sd], W1tl[sd], A1[sd], 2 * mB);
        }

    for (int it = 0; it < 4; ++it) {
        for (int sd = 0; sd < 2; ++sd) {
            r_kernel<<<32, 128, 0, stream>>>(h, us, ue, WD_w[sd], WD_b[sd], r);
            rterm_kernel<<<dim3(8, 32), 256, 0, stream>>>(
                r, W1_w[sd] + (size_t)256 * cN, W1_b[sd], rterm);
            // m1 rows [0, a1r): memory pass over fp32 A1
            if (a1r[sd] > 0)
                m1_from_a1_kernel<<<a1r[sd] / 2, 256, 0, stream>>>(
                    A1[sd], rterm, m1, m1h, m1l);
            // m1 rows [a1r, cM): fused MFMA GEMM
            if (a1r[sd] < cM) {
                int mB = (cM - a1r[sd]) / 128;
                mfma_pool_swp<<<16 * mB, 256, 0, stream>>>(
                    W1th[sd], W1tl[sd], Uh, Ul, rterm, cN, m1, m1h, m1l,
                    a1r[sd], 2 * mB);
            }
            // m2 = pool(m1 @ W2 + b2) -> fp32 (multi-subtile, unroll-1)
            mfma_pool_m2<<<1024, 256, 0, stream>>>(
                W2th[sd], W2tl[sd], m1h, m1l, W2_b[sd], m2);
            float* ent = outf + 64 + (size_t)(it * 2 + sd) * cB * cT;
            score_kernel<<<2048, 256, 0, stream>>>(m1, m2, W3_w[sd], W3_b[sd], ent);
            argmax_kernel<<<32, 256, 0, stream>>>(ent, U, sd ? ue : us,
                                                  outf + (sd ? 32 : 0));
        }
        lstm_kernel<<<32, 128, 0, stream>>>(us, ue, h, c, wih, whh, bih, bhh);
    }
}